// Round 1
// baseline (288.910 us; speedup 1.0000x reference)
//
#include <hip/hip_runtime.h>

#define T_ 4
#define C_ 3
#define H_ 128
#define W_ 128
#define PS_ 5
#define K_ 14
#define WS_ 15
#define SW_ 7
#define PW_ 2
#define RAD_ 9
#define HP_ (H_ + 2*RAD_)   // 146
#define NOFF (WS_*WS_)      // 225

#define TILE 16
#define LR 34    // LDS region rows/cols (TILE + 18)
#define LSTR 40  // LDS row stride (2-way bank aliasing only)

// ---------------- Kernel 1: per-(t,c) means of normalized image ----------------
__global__ __launch_bounds__(256) void means_kernel(const float* __restrict__ noisy,
                                                    float* __restrict__ means) {
    int tc = blockIdx.x; // 0..11
    const float* img = noisy + (size_t)tc * (H_*W_);
    float s = 0.f;
    for (int e = threadIdx.x; e < H_*W_; e += 256) s += img[e];
    #pragma unroll
    for (int off = 32; off; off >>= 1) s += __shfl_down(s, off, 64);
    __shared__ float red[4];
    int lane = threadIdx.x & 63, wv = threadIdx.x >> 6;
    if (lane == 0) red[wv] = s;
    __syncthreads();
    if (threadIdx.x == 0) {
        float tot = red[0] + red[1] + red[2] + red[3];
        means[tc] = tot / (float)(H_*W_) * (1.0f/127.5f) - 1.0f;
    }
}

// ---------------- Kernel 2: normalize + mean-subtract + reflect pad ----------------
__global__ __launch_bounds__(256) void pad_kernel(const float* __restrict__ noisy,
                                                  const float* __restrict__ means,
                                                  float* __restrict__ P) {
    int total = T_*C_*HP_*HP_;
    int e = blockIdx.x * 256 + threadIdx.x;
    if (e >= total) return;
    int x  = e % HP_;
    int y  = (e / HP_) % HP_;
    int tc = e / (HP_*HP_);
    int ry = y - RAD_; if (ry < 0) ry = -ry; else if (ry > H_-1) ry = 2*(H_-1) - ry;
    int rx = x - RAD_; if (rx < 0) rx = -rx; else if (rx > W_-1) rx = 2*(W_-1) - rx;
    P[e] = noisy[(size_t)tc*(H_*W_) + ry*W_ + rx] * (1.0f/127.5f) - 1.0f - means[tc];
}

// ---------------- Kernel 3: per-pixel 225 distances -> top-14 -> softmax weights ----------------
__global__ __launch_bounds__(256) void topk_kernel(const float* __restrict__ P,
                                                   const float* __restrict__ sigma,
                                                   float* __restrict__ wts,
                                                   int* __restrict__ idxs) {
    __shared__ float sP[C_][LR][LSTR];
    const int tx = threadIdx.x, ty = threadIdx.y;
    const int tile_j = blockIdx.x, tile_i = blockIdx.y, t = blockIdx.z;
    const int i0 = tile_i * TILE, j0 = tile_j * TILE;
    const int tid = ty * TILE + tx;
    const float* Pt = P + (size_t)t * (C_*HP_*HP_);

    for (int e = tid; e < C_*LR*LR; e += 256) {
        int col = e % LR;
        int r   = (e / LR) % LR;
        int c   = e / (LR*LR);
        sP[c][r][col] = Pt[(size_t)c*(HP_*HP_) + (i0 + r)*HP_ + (j0 + col)];
    }
    __syncthreads();

    // base patch (this pixel's reference patch) into registers: [p][c][q]
    float base[PS_*C_*PS_];
    #pragma unroll
    for (int p = 0; p < PS_; ++p)
        #pragma unroll
        for (int c = 0; c < C_; ++c)
            #pragma unroll
            for (int q = 0; q < PS_; ++q)
                base[(p*C_+c)*PS_+q] = sP[c][ty + SW_ + p][tx + SW_ + q];

    float dbest[K_];
    int   ibest[K_];
    #pragma unroll
    for (int k = 0; k < K_; ++k) { dbest[k] = 1e30f; ibest[k] = 0; }

    for (int o = 0; o < NOFF; ++o) {
        int oy = o / WS_, ox = o % WS_;
        float d = 0.f;
        #pragma unroll
        for (int p = 0; p < PS_; ++p)
            #pragma unroll
            for (int c = 0; c < C_; ++c)
                #pragma unroll
                for (int q = 0; q < PS_; ++q) {
                    float diff = base[(p*C_+c)*PS_+q] - sP[c][ty + oy + p][tx + ox + q];
                    d += diff * diff;
                }
        // stable insert into ascending sorted list (ties keep lowest offset index)
        if (d < dbest[K_-1]) {
            dbest[K_-1] = d; ibest[K_-1] = o;
            #pragma unroll
            for (int k = K_-1; k > 0; --k) {
                if (dbest[k] < dbest[k-1]) {
                    float td = dbest[k]; dbest[k] = dbest[k-1]; dbest[k-1] = td;
                    int   ti = ibest[k]; ibest[k] = ibest[k-1]; ibest[k-1] = ti;
                }
            }
        }
    }

    float sig = sigma[0] * (1.0f/255.0f) * 2.0f;  // sigma/255/0.5
    float denom = 2.0f * (float)(C_*PS_*PS_) * (sig*sig) + 1e-8f;
    float m = dbest[0];
    float w[K_]; float sum = 0.f;
    #pragma unroll
    for (int k = 0; k < K_; ++k) { w[k] = expf(-(dbest[k] - m) / denom); sum += w[k]; }
    float inv = 1.0f / sum;

    int i = i0 + ty, j = j0 + tx;
    size_t bofs = (((size_t)t*H_ + i)*W_ + j) * K_;
    #pragma unroll
    for (int k = 0; k < K_; ++k) {
        wts[bofs + k]  = w[k] * inv;
        idxs[bofs + k] = ibest[k];
    }
}

// ---------------- Kernel 4: gather-aggregate + final affine ----------------
__global__ __launch_bounds__(256) void agg_kernel(const float* __restrict__ P,
                                                  const float* __restrict__ wts,
                                                  const int* __restrict__ idxs,
                                                  const float* __restrict__ means,
                                                  float* __restrict__ out) {
    int gid = blockIdx.x * 256 + threadIdx.x;
    if (gid >= T_*H_*W_) return;
    int jo = gid % W_;
    int io = (gid / W_) % H_;
    int t  = gid / (H_*W_);
    int y = io + PW_, x = jo + PW_;   // coords in the (Hp=132) accumulation grid == padded-P coords
    const float* Pt = P + (size_t)t * (C_*HP_*HP_);

    float s0 = 0.f, s1 = 0.f, s2 = 0.f;
    int count = 0;
    #pragma unroll
    for (int a = 0; a < PS_; ++a) {
        int qi = y - a; if (qi < 0 || qi >= H_) continue;
        #pragma unroll
        for (int b = 0; b < PS_; ++b) {
            int qj = x - b; if (qj < 0 || qj >= W_) continue;
            ++count;
            size_t bofs = (((size_t)t*H_ + qi)*W_ + qj) * K_;
            #pragma unroll
            for (int k = 0; k < K_; ++k) {
                float w = wts[bofs + k];
                int o = idxs[bofs + k];
                int oy = o / WS_, ox = o % WS_;
                int pr = (y + oy)*HP_ + (x + ox);
                s0 += w * Pt[pr];
                s1 += w * Pt[HP_*HP_ + pr];
                s2 += w * Pt[2*(HP_*HP_) + pr];
            }
        }
    }
    float invc = 1.0f / ((float)count + 1e-10f);
    float m0 = means[t*3+0], m1 = means[t*3+1], m2 = means[t*3+2];
    size_t obase = (size_t)t*(C_*H_*W_) + (size_t)io*W_ + jo;
    out[obase]            = 127.5f * (s0*invc + m0 + 1.0f);
    out[obase +   H_*W_]  = 127.5f * (s1*invc + m1 + 1.0f);
    out[obase + 2*(H_*W_)] = 127.5f * (s2*invc + m2 + 1.0f);
}

extern "C" void kernel_launch(void* const* d_in, const int* in_sizes, int n_in,
                              void* d_out, int out_size, void* d_ws, size_t ws_size,
                              hipStream_t stream) {
    const float* noisy = (const float*)d_in[0];
    const float* sigma = (const float*)d_in[1];
    float* out = (float*)d_out;
    float* ws  = (float*)d_ws;

    // workspace layout (floats):
    // [0,12)          means
    // [16, 255808)    P: 4*3*146*146 = 255792
    // [255808, 1173312)   wts: 4*128*128*14 = 917504
    // [1173312, 2090816)  idxs (int): 917504
    float* means = ws;
    float* P     = ws + 16;
    float* wts   = ws + 16 + (size_t)T_*C_*HP_*HP_;
    int*   idxs  = (int*)(wts + (size_t)T_*H_*W_*K_);

    hipLaunchKernelGGL(means_kernel, dim3(T_*C_), dim3(256), 0, stream, noisy, means);

    int padN = T_*C_*HP_*HP_;
    hipLaunchKernelGGL(pad_kernel, dim3((padN + 255)/256), dim3(256), 0, stream,
                       noisy, means, P);

    hipLaunchKernelGGL(topk_kernel, dim3(W_/TILE, H_/TILE, T_), dim3(TILE, TILE), 0, stream,
                       P, sigma, wts, idxs);

    int aggN = T_*H_*W_;
    hipLaunchKernelGGL(agg_kernel, dim3((aggN + 255)/256), dim3(256), 0, stream,
                       P, wts, idxs, means, out);
}